// Round 3
// baseline (442.306 us; speedup 1.0000x reference)
//
#include <hip/hip_runtime.h>
#include <hip/hip_bf16.h>

#define NB 2
#define NN 512
#define ND 64
#define NH 128

typedef __attribute__((ext_vector_type(8))) short short8;
typedef __attribute__((ext_vector_type(4))) float f32x4;

__device__ __forceinline__ short f2s(float x) {
    __hip_bfloat16 h = __float2bfloat16(x);
    return *reinterpret_cast<short*>(&h);
}

__device__ __forceinline__ short8 cvt8(const float* p) {
    f32x4 a = *(const f32x4*)p;
    f32x4 b = *(const f32x4*)(p + 4);
    short8 r;
    r[0] = f2s(a[0]); r[1] = f2s(a[1]); r[2] = f2s(a[2]); r[3] = f2s(a[3]);
    r[4] = f2s(b[0]); r[5] = f2s(b[1]); r[6] = f2s(b[2]); r[7] = f2s(b[3]);
    return r;
}

// ---------------------------------------------------------------------------
// Kernel A: bias[bn][h] = sum_d node[bn][d]*W_edge[d][h] + b_edge[h]   (fp32)
// ---------------------------------------------------------------------------
__global__ __launch_bounds__(128) void bias_kernel(
    const float* __restrict__ node,
    const float* __restrict__ W_edge,
    const float* __restrict__ b_edge,
    float* __restrict__ bias)
{
    int bn = blockIdx.x;
    int h = threadIdx.x;
    __shared__ float nrow[ND];
    if (h < ND) nrow[h] = node[bn * ND + h];
    __syncthreads();
    float acc = b_edge[h];
    #pragma unroll
    for (int d = 0; d < ND; d++)
        acc += nrow[d] * W_edge[d * NH + h];
    bias[bn * NH + h] = acc;
}

// ---------------------------------------------------------------------------
// Kernel B: per (b,i):  edge_h[j,h] = relu([ef[j]|node[j]] @ [W3;W2] + bias_i)
//           message[i,h] = sum_j adj[i,j]*edge_h[j,h]
// MFMA 16x16x32 bf16; K=128 (ef 64 || node 64). One block per (b,i).
// fp32 inputs -> bf16 fragments on the fly; fp32 outputs.
// ---------------------------------------------------------------------------
__global__ __launch_bounds__(256) void edge_kernel(
    const float* __restrict__ ef,       // B,N,N,64 fp32
    const float* __restrict__ node,     // B,N,64 fp32
    const float* __restrict__ adj,      // B,N,N fp32
    const float* __restrict__ W_edge,   // 192,128 fp32
    const float* __restrict__ bias,     // B,N,128 fp32
    float* __restrict__ edge_out,       // B,N,N,128 fp32
    float* __restrict__ message)        // B,N,128 fp32
{
    constexpr int BTS = NH + 8;          // 136: 16B-aligned rows, conflict-free
    __shared__ short BT[NH * BTS];       // BT[h][k] = bf16(Bmat[k][h])
    __shared__ float msgbuf[4][NH];

    int blk = blockIdx.x;                // b*N + i
    int b = blk >> 9;
    int tid = threadIdx.x;

    // Stage BT: Bmat[k][h] = W_edge[(k<64 ? 128+k : k)][h]  (W3 top, W2 below)
    for (int t = tid; t < NH * NH; t += 256) {
        int h = t >> 7;
        int k = t & 127;
        int row = (k < ND) ? (2 * ND + k) : k;
        BT[h * BTS + k] = f2s(W_edge[row * NH + h]);
    }
    __syncthreads();

    int lane = tid & 63;
    int wave = tid >> 6;
    int m = lane & 15;        // M index (j in tile) for A; N index (h) for B/C
    int quad = lane >> 4;

    float bias_l[8];
    #pragma unroll
    for (int ht = 0; ht < 8; ht++)
        bias_l[ht] = bias[blk * NH + ht * 16 + m];

    float msg_l[8] = {0.f, 0.f, 0.f, 0.f, 0.f, 0.f, 0.f, 0.f};

    const float* adjrow = adj + (size_t)blk * NN;
    float* outbase = edge_out + (size_t)blk * NN * NH;

    for (int c = 0; c < 8; c++) {
        int j0 = wave * 128 + c * 16;
        int jm = j0 + m;
        const float* efp = ef + ((size_t)blk * NN + jm) * ND;
        const float* ndp = node + ((size_t)b * NN + jm) * ND;
        short8 af[4];
        af[0] = cvt8(efp + quad * 8);        // k 0..31   (edge feats)
        af[1] = cvt8(efp + 32 + quad * 8);   // k 32..63
        af[2] = cvt8(ndp + quad * 8);        // k 64..95  (node_j feats)
        af[3] = cvt8(ndp + 32 + quad * 8);   // k 96..127

        float av[4];
        #pragma unroll
        for (int r = 0; r < 4; r++)
            av[r] = adjrow[j0 + quad * 4 + r];

        #pragma unroll
        for (int ht = 0; ht < 8; ht++) {
            f32x4 acc = {0.f, 0.f, 0.f, 0.f};
            const short* bt = BT + (ht * 16 + m) * BTS;
            #pragma unroll
            for (int kf = 0; kf < 4; kf++) {
                short8 bfr = *(const short8*)(bt + kf * 32 + quad * 8);
                acc = __builtin_amdgcn_mfma_f32_16x16x32_bf16(af[kf], bfr, acc, 0, 0, 0);
            }
            int h = ht * 16 + m;
            float bsum = bias_l[ht];
            #pragma unroll
            for (int r = 0; r < 4; r++) {
                float v = acc[r] + bsum;
                v = fmaxf(v, 0.f);
                int j = j0 + quad * 4 + r;
                outbase[(size_t)j * NH + h] = v;
                msg_l[ht] += av[r] * v;
            }
        }
    }

    // Reduce message over quads (lanes sharing m), then over waves via LDS.
    #pragma unroll
    for (int ht = 0; ht < 8; ht++) {
        float v = msg_l[ht];
        v += __shfl_xor(v, 16, 64);
        v += __shfl_xor(v, 32, 64);
        if (quad == 0) msgbuf[wave][ht * 16 + m] = v;
    }
    __syncthreads();
    if (tid < NH) {
        float s = msgbuf[0][tid] + msgbuf[1][tid] + msgbuf[2][tid] + msgbuf[3][tid];
        message[(size_t)blk * NH + tid] = s;
    }
}

// ---------------------------------------------------------------------------
// Kernel C: ending[bn][k] = relu(msg[bn]@Wf1[:,k] + node[bn]@Wf2[:,k] + b_feat[k])
// ---------------------------------------------------------------------------
__global__ __launch_bounds__(128) void out_kernel(
    const float* __restrict__ node,
    const float* __restrict__ message,
    const float* __restrict__ W_feat,   // 192,128 fp32
    const float* __restrict__ b_feat,
    float* __restrict__ ending)
{
    int bn = blockIdx.x;
    int k = threadIdx.x;
    __shared__ float mrow[NH];
    __shared__ float nrow[ND];
    mrow[k] = message[(size_t)bn * NH + k];
    if (k < ND) nrow[k] = node[bn * ND + k];
    __syncthreads();
    float acc = b_feat[k];
    #pragma unroll 4
    for (int h = 0; h < NH; h++)
        acc += mrow[h] * W_feat[h * NH + k];
    #pragma unroll 4
    for (int d = 0; d < ND; d++)
        acc += nrow[d] * W_feat[(NH + d) * NH + k];
    ending[(size_t)bn * NH + k] = fmaxf(acc, 0.f);
}

// ---------------------------------------------------------------------------
extern "C" void kernel_launch(void* const* d_in, const int* in_sizes, int n_in,
                              void* d_out, int out_size, void* d_ws, size_t ws_size,
                              hipStream_t stream)
{
    const float* node   = (const float*)d_in[0];
    const float* adj    = (const float*)d_in[1];
    const float* tgt    = (const float*)d_in[2];
    const float* ef     = (const float*)d_in[3];
    // d_in[4] = node_mask (unused by reference)
    const float* W_edge = (const float*)d_in[5];
    const float* b_edge = (const float*)d_in[6];
    const float* W_feat = (const float*)d_in[7];
    const float* b_feat = (const float*)d_in[8];

    float* out_ending = (float*)d_out;                           // B*N*H
    float* out_edge   = out_ending + (size_t)NB * NN * NH;       // B*N*N*H
    float* out_tgt    = out_edge + (size_t)NB * NN * NN * NH;    // B*N*D

    float* bias    = (float*)d_ws;                    // B*N*H fp32
    float* message = bias + (size_t)NB * NN * NH;     // B*N*H fp32

    bias_kernel<<<NB * NN, NH, 0, stream>>>(node, W_edge, b_edge, bias);
    edge_kernel<<<NB * NN, 256, 0, stream>>>(ef, node, adj, W_edge, bias, out_edge, message);
    out_kernel<<<NB * NN, NH, 0, stream>>>(node, message, W_feat, b_feat, out_ending);
    hipMemcpyAsync(out_tgt, tgt, (size_t)NB * NN * ND * sizeof(float),
                   hipMemcpyDeviceToDevice, stream);
}